// Round 15
// baseline (182.516 us; speedup 1.0000x reference)
//
#include <hip/hip_runtime.h>
#include <math.h>

#define NEG 0.2f
#define EPSV 1e-5f

typedef _Float16 v8h __attribute__((ext_vector_type(8)));
typedef _Float16 v4h __attribute__((ext_vector_type(4)));
typedef _Float16 v2h __attribute__((ext_vector_type(2)));
typedef __fp16   f16x2 __attribute__((ext_vector_type(2)));
typedef float    v4f __attribute__((ext_vector_type(4)));

__device__ __forceinline__ float lrelu(float v) { return fmaxf(v, NEG * v); }
__device__ __forceinline__ v4f lrelu4(v4f v) {
    return __builtin_elementwise_max(v, v * NEG);
}
__device__ __forceinline__ v2h lreluh2(v2h v) {
    return __builtin_elementwise_max(v, v * (_Float16)NEG);
}

// cvt_pkrtz returns __fp16x2; bit-cast to _Float16x2 (same layout)
__device__ __forceinline__ v2h pk(float a, float b) {
    union { f16x2 i; v2h o; } u;
    u.i = __builtin_amdgcn_cvt_pkrtz(a, b);
    return u.o;
}

#define MFMA32(a, b, c) __builtin_amdgcn_mfma_f32_16x16x32_f16((a), (b), (c), 0, 0, 0)
#define MFMA16(a, b, c) __builtin_amdgcn_mfma_f32_16x16x16f16((a), (b), (c), 0, 0, 0)

// Round 15: deconfounded occupancy push. R13 config (XS staging, W2f in regs,
// best dur 69.5us at 2 waves/SIMD, total regs ~172 just over the 170 3-wave
// boundary) + exactly one change: WTf/WA2f (16 loop-invariant A-frag regs) ->
// LDS rows (stride 20h, <=2-way), re-read per iter under an asm memory
// clobber (stops R9-style LICM re-hoist). W2f STAYS in regs (R14 showed its
// LDS version costs conflicts + the XS drop doubled FETCH). LDS 53KB -> 3
// blocks/CU allowed; regs ~156 total -> 3 waves/SIMD.
__global__ __launch_bounds__(256, 3)
void gsl_mfma(const float* __restrict__ x,
              const float* __restrict__ trans_w, const float* __restrict__ trans_g,
              const float* __restrict__ trans_b, const float* __restrict__ trans_m,
              const float* __restrict__ trans_v,
              const float* __restrict__ pos_w1, const float* __restrict__ pos_g,
              const float* __restrict__ pos_b, const float* __restrict__ pos_m,
              const float* __restrict__ pos_v, const float* __restrict__ pos_w2,
              const float* __restrict__ pos_b2,
              const float* __restrict__ gate_w1, const float* __restrict__ gate_g,
              const float* __restrict__ gate_b, const float* __restrict__ gate_m,
              const float* __restrict__ gate_v, const float* __restrict__ gate_w2,
              const float* __restrict__ gate_b2,
              const float* __restrict__ attn_w1, const float* __restrict__ attn_g,
              const float* __restrict__ attn_b, const float* __restrict__ attn_m,
              const float* __restrict__ attn_v, const float* __restrict__ attn_w2,
              const float* __restrict__ attn_b2,
              float* __restrict__ out)
{
    __shared__ _Float16 WH[1920];        // WP1 4x(16x20) | WA1 16x20 | WG1 16x20
    __shared__ _Float16 WTL[1280];       // trans A-frags: 4 tiles x 16p x stride20
    __shared__ _Float16 WAL[1280];       // attn_w2 A-frags: 4 tiles x 16p x stride20
    __shared__ float    PB2[64];
    __shared__ _Float16 PHB[4][2][1152]; // per-wave dbuf: 16 pts x stride 72
    __shared__ _Float16 AHB[4][2][320];  // per-wave dbuf: 16 pts x stride 20
    __shared__ _Float16 XSB[4][2560];    // per-wave x: [k][pt][c] 20x16x8

    const int tid  = threadIdx.x;
    const int wv   = tid >> 6;
    const int lane = tid & 63;
    const int p    = lane & 15;
    const int q    = lane >> 4;

    const int b  = blockIdx.x >> 7;
    const int n0 = ((blockIdx.x & 127) << 6) | (wv << 4);
    const int n  = n0 | p;

    // ---- stage x into XS (coalesced float4 reads, one-time scatter writes) ----
    {
        const float* xw = x + ((size_t)b * 6 * 8192 + n0) * 20;
        _Float16* XS = &XSB[wv][0];
        #pragma unroll
        for (int i = 0; i < 8; ++i) {
            int idx = i * 64 + lane;          // 480 float4 per wave
            if (idx < 480) {
                int c  = idx / 80;            // 80 float4 per channel
                int rm = idx - c * 80;
                int pt = rm / 5;
                int k0 = (rm - pt * 5) * 4;
                const float4 v = *(const float4*)(xw + (size_t)c * 163840 + pt * 20 + k0);
                _Float16* dst = XS + pt * 8 + c;
                dst[(k0 + 0) * 128] = (_Float16)v.x;
                dst[(k0 + 1) * 128] = (_Float16)v.y;
                dst[(k0 + 2) * 128] = (_Float16)v.z;
                dst[(k0 + 3) * 128] = (_Float16)v.w;
            }
        }
        #pragma unroll
        for (int i = 0; i < 5; ++i) {         // bias columns c=6 (1.0), c=7 (0)
            int idx = i * 64 + lane;          // 320 (k,pt) slots
            int k = idx >> 4, pt = idx & 15;
            *(v2h*)(XS + k * 128 + pt * 8 + 6) = (v2h){(_Float16)1.f, (_Float16)0.f};
        }
    }

    // ---- stage produce-side + trans/attn2 weights in block-shared LDS ----
    if (tid < 64) {
        const int c = tid;
        float sp = pos_g[c] * rsqrtf(pos_v[c] + EPSV);
        float bp = pos_b[c] - pos_m[c] * sp;
        _Float16* row = WH + (c >> 4) * 320 + (c & 15) * 20;
        for (int k = 0; k < 20; ++k) {
            float v = (k >= 3 && k < 6) ? pos_w1[c * 3 + (k - 3)] * sp
                                        : ((k == 6) ? bp : 0.f);
            row[k] = (_Float16)v;
        }
        PB2[c] = pos_b2[c];
        // trans A-frag row (K=16, entries k=0..15)
        float st = trans_g[c] * rsqrtf(trans_v[c] + EPSV);
        float bt = trans_b[c] - trans_m[c] * st;
        _Float16* trow = WTL + (c >> 4) * 320 + (c & 15) * 20;
        for (int k = 0; k < 16; ++k)
            trow[k] = (_Float16)((k < 6) ? trans_w[c * 6 + k] * st
                                         : ((k == 6) ? bt : 0.f));
        // attn_w2 A-frag row (K=16, all real)
        _Float16* arow = WAL + (c >> 4) * 320 + (c & 15) * 20;
        for (int k = 0; k < 16; ++k)
            arow[k] = (_Float16)attn_w2[c * 16 + k];
    } else if (tid < 80) {
        const int j = tid - 64;
        float sa = attn_g[j] * rsqrtf(attn_v[j] + EPSV);
        float ba = attn_b[j] - attn_m[j] * sa;
        _Float16* row = WH + 1280 + j * 20;
        for (int k = 0; k < 20; ++k)
            row[k] = (_Float16)((k < 6) ? attn_w1[j * 6 + k] * sa
                                        : ((k == 6) ? ba : 0.f));
    } else if (tid < 96) {
        const int j = tid - 80;
        float sg = gate_g[j] * rsqrtf(gate_v[j] + EPSV);
        float bg = gate_b[j] - gate_m[j] * sg;
        _Float16* row = WH + 1600 + j * 20;
        for (int k = 0; k < 20; ++k)
            row[k] = (_Float16)((k < 6) ? gate_w1[j * 6 + k] * sg
                                        : ((k == 6) ? bg : 0.f));
    }

    // ---- persistent A-frags: only W2f (K=64 pe GEMM) stays in registers ----
    v8h W2f[4][2];
    #pragma unroll
    for (int mt = 0; mt < 4; ++mt) {
        const int ch = mt * 16 + p;
        #pragma unroll
        for (int h = 0; h < 2; ++h)
            #pragma unroll
            for (int i = 0; i < 8; ++i)
                W2f[mt][h][i] = (_Float16)pos_w2[ch * 64 + h * 32 + q * 8 + i];
    }
    float g2w[4];
    #pragma unroll
    for (int r = 0; r < 4; ++r) g2w[r] = gate_w2[4 * q + r];
    const float gb2v = gate_b2[0];

    __syncthreads();   // WH/WTL/WAL/PB2 visible to all waves

    const _Float16* const WP1p = WH + p * 20 + q * 4;          // + mt*320
    const _Float16* const WA1p = WH + 1280 + p * 20 + q * 4;
    const _Float16* const WG1p = WH + 1600 + p * 20 + q * 4;
    const _Float16* const WTLp = WTL + p * 20 + q * 4;         // + mt*320
    const _Float16* const WALp = WAL + p * 20 + q * 4;         // + mt*320
    const float* const    PB2p = PB2 + 4 * q;                  // + mt*16
    const _Float16* const XS   = &XSB[wv][0];

    _Float16* const PHbase = &PHB[wv][0][0];
    _Float16* const AHbase = &AHB[wv][0][0];

    const int xoff = p * 8 + (q & 1) * 4;   // q>=2: dup of q&1 (A-side k>=8 zero)

    const v4f zero = {0.f, 0.f, 0.f, 0.f};
    v4f den[4], num[4], cmx[4];
    #pragma unroll
    for (int mt = 0; mt < 4; ++mt) {
        den[mt] = zero; num[mt] = zero;
        cmx[mt] = (v4f){-3.4e38f, -3.4e38f, -3.4e38f, -3.4e38f};
    }

    // ---- pipeline prologue: k=0 produce ----
    v4h xv_cur = *(const v4h*)(XS + xoff);
    {
        v4f php[4];
        #pragma unroll
        for (int mt = 0; mt < 4; ++mt)
            php[mt] = MFMA16(*(const v4h*)(WP1p + mt * 320), xv_cur, zero);
        v4f ahp = MFMA16(*(const v4h*)WA1p, xv_cur, zero);
        _Float16* PHW = PHbase + p * 72 + 4 * q;
        #pragma unroll
        for (int mt = 0; mt < 4; ++mt) {
            union { v4h v; v2h h[2]; } u;
            u.h[0] = lreluh2(pk(php[mt][0], php[mt][1]));
            u.h[1] = lreluh2(pk(php[mt][2], php[mt][3]));
            *(v4h*)(PHW + mt * 16) = u.v;
        }
        union { v4h v; v2h h[2]; } ua;
        ua.h[0] = lreluh2(pk(ahp[0], ahp[1]));
        ua.h[1] = lreluh2(pk(ahp[2], ahp[3]));
        *(v4h*)(AHbase + p * 20 + 4 * q) = ua.v;
    }

    #pragma unroll 1
    for (int k = 0; k < 20; ++k) {
        // keep in-loop LDS weight reads in-loop (LICM would re-hoist them
        // into the registers we just freed — R9's measured failure mode)
        asm volatile("" ::: "memory");

        const int sel = k & 1;
        // 1) issue reads for k (writes landed last iteration)
        _Float16* PH = PHbase + sel * 1152;
        _Float16* AH = AHbase + sel * 320;
        v8h phf0 = *(const v8h*)(PH + p * 72 + 8 * q);
        v8h phf1 = *(const v8h*)(PH + p * 72 + 32 + 8 * q);
        v4h ahf  = *(const v4h*)(AH + p * 20 + 4 * q);  // read == write addr

        // 2) produce(k+1) into the other buffer
        v4h xv_nxt = xv_cur;
        if (k < 19) {
            xv_nxt = *(const v4h*)(XS + (k + 1) * 128 + xoff);
            v4f php[4];
            #pragma unroll
            for (int mt = 0; mt < 4; ++mt)
                php[mt] = MFMA16(*(const v4h*)(WP1p + mt * 320), xv_nxt, zero);
            v4f ahp = MFMA16(*(const v4h*)WA1p, xv_nxt, zero);
            _Float16* PHW = PHbase + (sel ^ 1) * 1152 + p * 72 + 4 * q;
            #pragma unroll
            for (int mt = 0; mt < 4; ++mt) {
                union { v4h v; v2h h[2]; } uu;
                uu.h[0] = lreluh2(pk(php[mt][0], php[mt][1]));
                uu.h[1] = lreluh2(pk(php[mt][2], php[mt][3]));
                *(v4h*)(PHW + mt * 16) = uu.v;
            }
            union { v4h v; v2h h[2]; } ua;
            ua.h[0] = lreluh2(pk(ahp[0], ahp[1]));
            ua.h[1] = lreluh2(pk(ahp[2], ahp[3]));
            *(v4h*)(AHbase + (sel ^ 1) * 320 + p * 20 + 4 * q) = ua.v;
        }

        // 3) consume(k): gate first (needed by every mt's cmx)
        v4f ghp = MFMA16(*(const v4h*)WG1p, xv_cur, zero);
        float ga = 0.f;
        #pragma unroll
        for (int r = 0; r < 4; ++r) ga += g2w[r] * lrelu(ghp[r]);
        ga += __shfl_xor(ga, 16);
        ga += __shfl_xor(ga, 32);
        const float gate = 1.f / (1.f + __expf(-(ga + gb2v)));

        // per-mt streaming; WTf/WA2f frags re-read from LDS (clobber holds)
        #pragma unroll
        for (int mt = 0; mt < 4; ++mt) {
            v4f pe = MFMA32(W2f[mt][0], phf0, *(const v4f*)(PB2p + mt * 16));
            pe = MFMA32(W2f[mt][1], phf1, pe);
            v4f tfa = MFMA16(*(const v4h*)(WTLp + mt * 320), xv_cur, zero);
            v4f tfv = lrelu4(tfa) + pe;
            pe = MFMA16(*(const v4h*)(WALp + mt * 320), ahf, pe);  // logits
            v4f e;
            #pragma unroll
            for (int r = 0; r < 4; ++r) e[r] = __expf(pe[r]);
            den[mt] += e;
            num[mt] += tfv * e;
            cmx[mt] = __builtin_elementwise_max(cmx[mt], tfv * gate);
        }
        xv_cur = xv_nxt;
    }

    // write out: lane owns channels mt*16 + 4q + r for its point n
    #pragma unroll
    for (int mt = 0; mt < 4; ++mt) {
        #pragma unroll
        for (int r = 0; r < 4; ++r) {
            const int ch = mt * 16 + 4 * q + r;
            out[((size_t)(b * 64 + ch)) * 8192 + n] =
                num[mt][r] / den[mt][r] + cmx[mt][r];
        }
    }
}

extern "C" void kernel_launch(void* const* d_in, const int* in_sizes, int n_in,
                              void* d_out, int out_size, void* d_ws, size_t ws_size,
                              hipStream_t stream) {
    const float* x       = (const float*)d_in[0];
    const float* trans_w = (const float*)d_in[1];
    const float* trans_g = (const float*)d_in[2];
    const float* trans_b = (const float*)d_in[3];
    const float* trans_m = (const float*)d_in[4];
    const float* trans_v = (const float*)d_in[5];
    const float* pos_w1  = (const float*)d_in[6];
    const float* pos_g   = (const float*)d_in[7];
    const float* pos_b   = (const float*)d_in[8];
    const float* pos_m   = (const float*)d_in[9];
    const float* pos_v   = (const float*)d_in[10];
    const float* pos_w2  = (const float*)d_in[11];
    const float* pos_b2  = (const float*)d_in[12];
    const float* gate_w1 = (const float*)d_in[13];
    const float* gate_g  = (const float*)d_in[14];
    const float* gate_b  = (const float*)d_in[15];
    const float* gate_m  = (const float*)d_in[16];
    const float* gate_v  = (const float*)d_in[17];
    const float* gate_w2 = (const float*)d_in[18];
    const float* gate_b2 = (const float*)d_in[19];
    const float* attn_w1 = (const float*)d_in[20];
    const float* attn_g  = (const float*)d_in[21];
    const float* attn_b  = (const float*)d_in[22];
    const float* attn_m  = (const float*)d_in[23];
    const float* attn_v  = (const float*)d_in[24];
    const float* attn_w2 = (const float*)d_in[25];
    const float* attn_b2 = (const float*)d_in[26];
    float* out = (float*)d_out;

    // 8 b * 128 blocks/b; block = 4 waves * 16 points
    gsl_mfma<<<1024, 256, 0, stream>>>(
        x, trans_w, trans_g, trans_b, trans_m, trans_v,
        pos_w1, pos_g, pos_b, pos_m, pos_v, pos_w2, pos_b2,
        gate_w1, gate_g, gate_b, gate_m, gate_v, gate_w2, gate_b2,
        attn_w1, attn_g, attn_b, attn_m, attn_v, attn_w2, attn_b2,
        out);
}